// Round 6
// baseline (151.450 us; speedup 1.0000x reference)
//
#include <hip/hip_runtime.h>
#include <hip/hip_bf16.h>

#define IMG_W 1024
#define IMG_H 1024
#define TH    8           // output rows per block: 2048 blocks -> 8 blocks/CU
#define VX    4           // pixels per thread (float4)
#define NTHREADS 256      // 256*4 = 1024 = full row width

#define ALPHA_ 0.85f
#define BETA_  0.15f
// scale-invariant constants: 81*C1, 81*C2
#define K1_ (81.0f * (0.01f * 0.01f))
#define K2_ (81.0f * (0.03f * 0.03f))

// Load one row: two float4 (coalesced) + ONE predicated dword per array for
// the wave-edge lanes (lane 0 needs x-1, lane 63 needs x+4; interior lanes
// get edges via shuffle). Replaces R5's 4 full scalar edge loads.
__device__ __forceinline__ void row_loads(const float* __restrict__ Pr,
                                          const float* __restrict__ Tr,
                                          int x, int lane,
                                          float4& p4, float4& t4,
                                          float& pe, float& te) {
    p4 = *reinterpret_cast<const float4*>(Pr + x);
    t4 = *reinterpret_cast<const float4*>(Tr + x);
    const bool lo = (lane == 0)  && (x > 0);
    const bool hi = (lane == 63) && (x + VX < IMG_W);
    pe = 0.f; te = 0.f;
    if (lo || hi) {                    // <=2 active lanes, exec-masked loads
        const int ex = hi ? (x + VX) : (x - 1);
        pe = Pr[ex];
        te = Tr[ex];
    }
}

// Horizontal 3-sum stats for this thread's VX pixels from loaded row data.
__device__ __forceinline__ void row_stats(const float4& p4, const float4& t4,
                                          float pe, float te, int lane,
                                          float cp[VX], float ct[VX],
                                          float cpp[VX], float ctt[VX],
                                          float cpt[VX]) {
    float pv[6], tv[6];
    pv[1] = p4.x; pv[2] = p4.y; pv[3] = p4.z; pv[4] = p4.w;
    tv[1] = t4.x; tv[2] = t4.y; tv[3] = t4.z; tv[4] = t4.w;
    const float pmu = __shfl_up(p4.w, 1, 64);
    const float tmu = __shfl_up(t4.w, 1, 64);
    const float pmd = __shfl_down(p4.x, 1, 64);
    const float tmd = __shfl_down(t4.x, 1, 64);
    pv[0] = (lane == 0)  ? pe : pmu;
    tv[0] = (lane == 0)  ? te : tmu;
    pv[5] = (lane == 63) ? pe : pmd;
    tv[5] = (lane == 63) ? te : tmd;
#pragma unroll
    for (int j = 0; j < VX; ++j) {
        const float a = pv[j], b = pv[j + 1], c = pv[j + 2];
        const float u = tv[j], v = tv[j + 1], w = tv[j + 2];
        cp[j]  = a + b + c;
        ct[j]  = u + v + w;
        cpp[j] = fmaf(a, a, fmaf(b, b, c * c));
        ctt[j] = fmaf(u, u, fmaf(v, v, w * w));
        cpt[j] = fmaf(a, u, fmaf(b, v, c * w));
    }
}

// MODE=0: per-block partials to ws[2*bid]; MODE=1: atomics (small-ws fallback).
// No min-waves bound (R4: forcing 8/EU spilled to scratch, 557MB writes).
// Row loop stays rolled (R3: trip-count-8 auto-unroll -> 108 VGPR).
template <int MODE>
__global__ void __launch_bounds__(NTHREADS)
ssim_l1_kernel(const float* __restrict__ pred, const float* __restrict__ tgt,
               float* __restrict__ ws) {
    const int tid  = threadIdx.x;
    const int lane = tid & 63;
    const int x    = tid * VX;
    const int y0   = blockIdx.y * TH;
    const size_t base = (size_t)blockIdx.z * (size_t)(IMG_W * IMG_H);
    const float* __restrict__ P = pred + base;
    const float* __restrict__ T = tgt + base;

    float ssim_acc = 0.f, l1_acc = 0.f;

    // 2-row persistent state: AB = rowsum(y-1)+rowsum(y), B = rowsum(y)
    float ABp[VX], ABt[VX], ABpp[VX], ABtt[VX], ABpt[VX];
    float Bcp[VX], Bct[VX], Bcpp[VX], Bctt[VX], Bcpt[VX];
    float cp[VX], ct[VX], cpp[VX], ctt[VX], cpt[VX];

    float4 p4, t4; float pe, te;

    // --- prologue: row y0-1 (zeros if above image) ---
    if (y0 > 0) {
        row_loads(P + (size_t)(y0 - 1) * IMG_W, T + (size_t)(y0 - 1) * IMG_W,
                  x, lane, p4, t4, pe, te);
        row_stats(p4, t4, pe, te, lane, ABp, ABt, ABpp, ABtt, ABpt);
    } else {
#pragma unroll
        for (int j = 0; j < VX; ++j) {
            ABp[j] = 0.f; ABt[j] = 0.f; ABpp[j] = 0.f; ABtt[j] = 0.f; ABpt[j] = 0.f;
        }
    }
    // --- row y0 (always valid): B; AB += B; L1 of owned row y0 ---
    {
        row_loads(P + (size_t)y0 * IMG_W, T + (size_t)y0 * IMG_W,
                  x, lane, p4, t4, pe, te);
        row_stats(p4, t4, pe, te, lane, Bcp, Bct, Bcpp, Bctt, Bcpt);
        l1_acc += fabsf(p4.x - t4.x) + fabsf(p4.y - t4.y)
                + fabsf(p4.z - t4.z) + fabsf(p4.w - t4.w);
#pragma unroll
        for (int j = 0; j < VX; ++j) {
            ABp[j] += Bcp[j];  ABt[j] += Bct[j];
            ABpp[j] += Bcpp[j]; ABtt[j] += Bctt[j]; ABpt[j] += Bcpt[j];
        }
    }

    // --- preload row y0+1 (always < IMG_H since y0 <= IMG_H-TH) ---
    row_loads(P + (size_t)(y0 + 1) * IMG_W, T + (size_t)(y0 + 1) * IMG_W,
              x, lane, p4, t4, pe, te);

    // --- main loop: software-pipelined, rolled ---
#pragma clang loop unroll(disable)
    for (int yo = y0; yo < y0 + TH; ++yo) {
        // consume the preloaded row (= row yo+1; zeros if it was invalid)
        row_stats(p4, t4, pe, te, lane, cp, ct, cpp, ctt, cpt);
        if (yo + 1 < y0 + TH) {     // row yo+1 owned by this block -> L1 term
            l1_acc += fabsf(p4.x - t4.x) + fabsf(p4.y - t4.y)
                    + fabsf(p4.z - t4.z) + fabsf(p4.w - t4.w);
        }
        // immediately reissue loads for row yo+2 (overlaps the SSIM math)
        {
            const int r2 = yo + 2;
            if ((r2 <= y0 + TH) && (r2 < IMG_H)) {
                row_loads(P + (size_t)r2 * IMG_W, T + (size_t)r2 * IMG_W,
                          x, lane, p4, t4, pe, te);
            } else {
                p4 = make_float4(0.f, 0.f, 0.f, 0.f);
                t4 = make_float4(0.f, 0.f, 0.f, 0.f);
                pe = 0.f; te = 0.f;
            }
        }

#pragma unroll
        for (int j = 0; j < VX; ++j) {
            const float Sp  = ABp[j]  + cp[j];
            const float St  = ABt[j]  + ct[j];
            const float Spp = ABpp[j] + cpp[j];
            const float Stt = ABtt[j] + ctt[j];
            const float Spt = ABpt[j] + cpt[j];

            // roll: AB <- B + c ; B <- c
            ABp[j]  = Bcp[j]  + cp[j];  Bcp[j]  = cp[j];
            ABt[j]  = Bct[j]  + ct[j];  Bct[j]  = ct[j];
            ABpp[j] = Bcpp[j] + cpp[j]; Bcpp[j] = cpp[j];
            ABtt[j] = Bctt[j] + ctt[j]; Bctt[j] = ctt[j];
            ABpt[j] = Bcpt[j] + cpt[j]; Bcpt[j] = cpt[j];

            // scale-invariant SSIM: multiply n,d by 81^2 (cancels in ratio)
            const float SpSt = Sp * St;
            const float Sp2  = Sp * Sp;
            const float St2  = St * St;
            const float n1 = fmaf(2.0f, SpSt, K1_);
            const float n2 = fmaf(-2.0f, SpSt, fmaf(18.0f, Spt, K2_));
            const float d1 = (Sp2 + St2) + K1_;
            const float d2 = (fmaf(9.0f, Spp, K2_) + fmaf(9.0f, Stt, -Sp2)) - St2;
            const float num = n1 * n2;
            const float den = d1 * d2;                    // > 0 (Cauchy-Schwarz)
            const float ssim = num * __builtin_amdgcn_rcpf(den);
            float vcl = fmaf(-0.5f, ssim, 0.5f);
            vcl = fminf(fmaxf(vcl, 0.0f), 1.0f);
            ssim_acc += vcl;
        }
    }

    // --- reduction: wave shuffle -> LDS across 4 waves -> one write/block ---
    float s = ssim_acc, l = l1_acc;
#pragma unroll
    for (int off = 32; off > 0; off >>= 1) {
        s += __shfl_down(s, off, 64);
        l += __shfl_down(l, off, 64);
    }
    __shared__ float red_s[NTHREADS / 64];
    __shared__ float red_l[NTHREADS / 64];
    const int wid = tid >> 6;
    if (lane == 0) { red_s[wid] = s; red_l[wid] = l; }
    __syncthreads();
    if (tid == 0) {
        float ss = 0.f, ll = 0.f;
#pragma unroll
        for (int w = 0; w < NTHREADS / 64; ++w) { ss += red_s[w]; ll += red_l[w]; }
        if (MODE == 0) {
            const int bid = blockIdx.z * gridDim.y + blockIdx.y;
            ws[2 * bid]     = ss;   // every slot written every call: no pre-zero
            ws[2 * bid + 1] = ll;
        } else {
            atomicAdd(&ws[0], ss);
            atomicAdd(&ws[1], ll);
        }
    }
}

__global__ void zero_ws_kernel(float* __restrict__ ws) {
    ws[0] = 0.f;
    ws[1] = 0.f;
}

__global__ void __launch_bounds__(256)
finalize_partials_kernel(const float* __restrict__ ws, float* __restrict__ out,
                         int nblocks, float inv_total) {
    const int tid = threadIdx.x;
    float s = 0.f, l = 0.f;
    for (int i = tid; i < nblocks; i += 256) {
        s += ws[2 * i];
        l += ws[2 * i + 1];
    }
#pragma unroll
    for (int off = 32; off > 0; off >>= 1) {
        s += __shfl_down(s, off, 64);
        l += __shfl_down(l, off, 64);
    }
    __shared__ float red_s[4], red_l[4];
    const int wid = tid >> 6, lane = tid & 63;
    if (lane == 0) { red_s[wid] = s; red_l[wid] = l; }
    __syncthreads();
    if (tid == 0) {
        float ss = red_s[0] + red_s[1] + red_s[2] + red_s[3];
        float ll = red_l[0] + red_l[1] + red_l[2] + red_l[3];
        out[0] = ALPHA_ * (ss * inv_total) + BETA_ * (ll * inv_total);
    }
}

__global__ void finalize_atomic_kernel(const float* __restrict__ ws,
                                       float* __restrict__ out, float inv_total) {
    out[0] = ALPHA_ * (ws[0] * inv_total) + BETA_ * (ws[1] * inv_total);
}

extern "C" void kernel_launch(void* const* d_in, const int* in_sizes, int n_in,
                              void* d_out, int out_size, void* d_ws, size_t ws_size,
                              hipStream_t stream) {
    const float* pred = (const float*)d_in[0];
    const float* tgt  = (const float*)d_in[1];
    float* ws = (float*)d_ws;

    const int total = in_sizes[0];                 // 16 * 1024 * 1024
    const int nimg  = total / (IMG_W * IMG_H);     // 16
    const int nblk  = nimg * (IMG_H / TH);         // 2048
    const float inv_total = 1.0f / (float)total;

    dim3 grid(1, IMG_H / TH, nimg);

    if (ws_size >= (size_t)(2 * nblk) * sizeof(float)) {
        ssim_l1_kernel<0><<<grid, NTHREADS, 0, stream>>>(pred, tgt, ws);
        finalize_partials_kernel<<<1, 256, 0, stream>>>(ws, (float*)d_out,
                                                        nblk, inv_total);
    } else {
        zero_ws_kernel<<<1, 1, 0, stream>>>(ws);
        ssim_l1_kernel<1><<<grid, NTHREADS, 0, stream>>>(pred, tgt, ws);
        finalize_atomic_kernel<<<1, 1, 0, stream>>>(ws, (float*)d_out, inv_total);
    }
}